// Round 13
// baseline (509.840 us; speedup 1.0000x reference)
//
#include <hip/hip_runtime.h>
#include <math.h>

// Problem constants (B=2, H=8, S=2048, D=64)
#define BH_    16
#define S_     2048
#define D_     64
#define KELEMS (BH_ * S_ * D_)   // 2,097,152 K elements
#define NROWS  (BH_ * S_)        // 32,768 query rows
#define QT     32                // queries per block (2 MFMA A-frags per wave)
#define BLOCK  1024              // 16 waves
#define NW     16
#define KTW    8                 // 16x16 C-tiles per wave: 128 keys/wave
#define CAP    448               // candidate cap at threshold m-1 (avg ~126,
                                 // Gumbel tail to ~500; overflow -> repair)
#define RSTR   449               // padded row stride (449 % 32 == 1: no bank alias)
#define WMAXIT 24                // exact row Newton max iters (early-exit)
#define SUPR   256               // repair-kernel support cap

typedef __attribute__((ext_vector_type(8))) short bf16x8;   // 8 bf16 = 4 VGPR
typedef __attribute__((ext_vector_type(4))) float f32x4;

// Exact hi/lo bf16 truncation split of 8 consecutive floats.
// x = hi + lo + eps, |eps| <= 2^-15 |x|; products use hh + hl + lh (drop ll).
__device__ __forceinline__ void split8(const float4 f0, const float4 f1,
                                       bf16x8& hi, bf16x8& lo) {
  union { bf16x8 v; unsigned int u[4]; } H, L;
  const float ff[8] = {f0.x, f0.y, f0.z, f0.w, f1.x, f1.y, f1.z, f1.w};
#pragma unroll
  for (int p = 0; p < 4; ++p) {
    unsigned int b0 = __float_as_uint(ff[2 * p]);
    unsigned int b1 = __float_as_uint(ff[2 * p + 1]);
    unsigned int h0 = b0 & 0xFFFF0000u;
    unsigned int h1 = b1 & 0xFFFF0000u;
    H.u[p] = (h0 >> 16) | h1;                       // lo short = elem 2p
    float l0 = ff[2 * p]     - __uint_as_float(h0); // exact in fp32
    float l1 = ff[2 * p + 1] - __uint_as_float(h1);
    L.u[p] = (__float_as_uint(l0) >> 16) | (__float_as_uint(l1) & 0xFFFF0000u);
  }
  hi = H.v; lo = L.v;
}

// Prepass: K fp32 -> (Khi, Klo) bf16, same element order; zero overflow flags.
__global__ __launch_bounds__(256)
void ksplit_kernel(const float* __restrict__ k,
                   unsigned short* __restrict__ khi,
                   unsigned short* __restrict__ klo,
                   int* __restrict__ gflag) {
  const int gi = blockIdx.x * 256 + threadIdx.x;
  if (gflag != nullptr && gi < NROWS) gflag[gi] = 0;
  const int i = gi * 4;
  float4 x = *(const float4*)(k + i);
  ushort4 h, l;
  {
    unsigned int b;
    b = __float_as_uint(x.x); h.x = (unsigned short)(b >> 16);
    l.x = (unsigned short)(__float_as_uint(x.x - __uint_as_float(b & 0xFFFF0000u)) >> 16);
    b = __float_as_uint(x.y); h.y = (unsigned short)(b >> 16);
    l.y = (unsigned short)(__float_as_uint(x.y - __uint_as_float(b & 0xFFFF0000u)) >> 16);
    b = __float_as_uint(x.z); h.z = (unsigned short)(b >> 16);
    l.z = (unsigned short)(__float_as_uint(x.z - __uint_as_float(b & 0xFFFF0000u)) >> 16);
    b = __float_as_uint(x.w); h.w = (unsigned short)(b >> 16);
    l.w = (unsigned short)(__float_as_uint(x.w - __uint_as_float(b & 0xFFFF0000u)) >> 16);
  }
  *(ushort4*)(khi + i) = h;
  *(ushort4*)(klo + i) = l;
}

// ============ Main kernel: R12 minus the 5-pass segment Newton ============
// R12 accounting: the segment Newton was ~2050 of ~7000 VALU ops/thread, all
// to tighten the compaction threshold. Threshold m-1 (m = global row max) is
// provably <= tau* (sum p = 1, each p <= 1), and overflow past CAP is repair-
// backed, so the pre-Newton buys nothing correctness needs. Epilogue Newton
// simply starts colder (m-1, ~11 iters on 7 regs).
template <bool PRE>
__global__ __launch_bounds__(BLOCK, 4)   // acc=64 AGPR -> 4 waves/SIMD
void entmax_attn_kernel(const float* __restrict__ q,
                        const float* __restrict__ k,
                        const unsigned short* __restrict__ khi,
                        const unsigned short* __restrict__ klo,
                        const float* __restrict__ v,
                        int* __restrict__ gflag,
                        float* __restrict__ out) {
  __shared__ unsigned int cnt[QT];     // TRUE candidate counts (un-clamped)
  __shared__ float smax[QT][17];       // per-(row, segment) max; stride 17
                                       // (coprime 32) -> conflict-free reads
  __shared__ int   lidx[QT * RSTR];    // candidates: key index  (57.4 KB)
  __shared__ float lval[QT * RSTR];    // candidates: x, then p  (57.4 KB)

  const int t    = threadIdx.x;
  const int wid  = t >> 6;             // 0..15 (= key segment)
  const int lane = t & 63;
  const int g    = lane >> 4;          // lane group 0..3
  const int col  = lane & 15;          // MFMA col (key) / A-row index

  // head-XCD affinity: bh = blk & 15 -> blk % 8 == bh % 8 under round-robin.
  const int blk = blockIdx.x;
  const int bh  = blk & 15;
  const int qt  = blk >> 4;            // 0..63
  const float* qp = q + ((size_t)bh * S_ + (size_t)qt * QT) * D_;
  const float* kp = k + (size_t)bh * S_ * D_;
  const float* vp = v + (size_t)bh * S_ * D_;
  float* op = out + ((size_t)bh * S_ + (size_t)qt * QT) * D_;

  if (t < QT) cnt[t] = 0;

  // ---- Q fragments: A-frag f covers rows f*16..f*16+15 (row = col).
  // Fold scale (1/8) and entmax /2 => *1/16 (power of 2: exact prescale).
  bf16x8 qh[2][2], ql[2][2];
#pragma unroll
  for (int f = 0; f < 2; ++f)
#pragma unroll
    for (int ks = 0; ks < 2; ++ks) {
      const float* src = qp + (f * 16 + col) * D_ + ks * 32 + g * 8;
      float4 f0 = *(const float4*)src;
      float4 f1 = *(const float4*)(src + 4);
      f0.x *= 0.0625f; f0.y *= 0.0625f; f0.z *= 0.0625f; f0.w *= 0.0625f;
      f1.x *= 0.0625f; f1.y *= 0.0625f; f1.z *= 0.0625f; f1.w *= 0.0625f;
      split8(f0, f1, qh[f][ks], ql[f][ks]);
    }

  // ---- QK^T: acc[f][kt][j] = x[row=f*16+g*4+j][key=wid*128+kt*16+col].
  // fp32-ish accuracy: qh*kh + qh*kl + ql*kh (drop ll, ~2^-15 rel).
  f32x4 acc[2][KTW];
#pragma unroll
  for (int f = 0; f < 2; ++f)
#pragma unroll
    for (int kt = 0; kt < KTW; ++kt) acc[f][kt] = (f32x4){0.f, 0.f, 0.f, 0.f};
#pragma unroll
  for (int kt = 0; kt < KTW; ++kt) {
    const size_t rowoff = (size_t)(wid * 128 + kt * 16 + col) * D_;
#pragma unroll
    for (int ks = 0; ks < 2; ++ks) {
      bf16x8 kh, kl;
      if (PRE) {
        const size_t eoff = (size_t)bh * S_ * D_ + rowoff + ks * 32 + g * 8;
        kh = *(const bf16x8*)(khi + eoff);
        kl = *(const bf16x8*)(klo + eoff);
      } else {
        const float* src = kp + rowoff + ks * 32 + g * 8;
        split8(*(const float4*)src, *(const float4*)(src + 4), kh, kl);
      }
#pragma unroll
      for (int f = 0; f < 2; ++f) {
        acc[f][kt] = __builtin_amdgcn_mfma_f32_16x16x32_bf16(qh[f][ks], kh, acc[f][kt], 0, 0, 0);
        acc[f][kt] = __builtin_amdgcn_mfma_f32_16x16x32_bf16(qh[f][ks], kl, acc[f][kt], 0, 0, 0);
        acc[f][kt] = __builtin_amdgcn_mfma_f32_16x16x32_bf16(ql[f][ks], kh, acc[f][kt], 0, 0, 0);
      }
    }
  }

  // ---- wave-segment row max over this wave's 128 keys (16-lane butterfly).
  float m4[2][4];
#pragma unroll
  for (int f = 0; f < 2; ++f)
#pragma unroll
    for (int j = 0; j < 4; ++j) {
      float mm = acc[f][0][j];
#pragma unroll
      for (int kt = 1; kt < KTW; ++kt) mm = fmaxf(mm, acc[f][kt][j]);
      m4[f][j] = mm;
    }
#pragma unroll
  for (int off = 1; off < 16; off <<= 1)
#pragma unroll
    for (int f = 0; f < 2; ++f)
#pragma unroll
      for (int j = 0; j < 4; ++j)
        m4[f][j] = fmaxf(m4[f][j], __shfl_xor(m4[f][j], off, 64));

  // publish segment maxes (one writer per (row, wid)).
  if (col == 0) {
#pragma unroll
    for (int f = 0; f < 2; ++f)
#pragma unroll
      for (int j = 0; j < 4; ++j)
        smax[f * 16 + g * 4 + j][wid] = m4[f][j];
  }
  __syncthreads();   // barrier 1: smax + cnt init visible

  // ---- per-lane global row max (row = lane&31; lanes l and l+32 duplicate).
  // Padded stride-17 reads: lanes 0..31 hit 32 distinct banks per step.
  float rowmax;
  {
    const int r0 = lane & 31;
    rowmax = smax[r0][0];
#pragma unroll
    for (int s = 1; s < NW; ++s) rowmax = fmaxf(rowmax, smax[r0][s]);
  }
  // thresholds for this thread's 8 rows: thr = m - 1 <= tau* (provable).
  float thr[2][4];
#pragma unroll
  for (int f = 0; f < 2; ++f)
#pragma unroll
    for (int j = 0; j < 4; ++j)
      thr[f][j] = __shfl(rowmax, f * 16 + g * 4 + j) - 1.0f;

  // ---- compaction: group-aggregated atomic (one atomicAdd per 16-lane
  // ballot group, ~4x fewer serialized LDS-atomic round trips than
  // per-candidate) + prefix-popcount slots. TRUE counts preserved.
#pragma unroll
  for (int kt = 0; kt < KTW; ++kt)
#pragma unroll
    for (int f = 0; f < 2; ++f)
#pragma unroll
      for (int j = 0; j < 4; ++j) {
        const float x = acc[f][kt][j];
        const bool pred = x > thr[f][j];
        const unsigned long long mb = __ballot(pred);
        const unsigned int field = (unsigned int)(mb >> (g * 16)) & 0xFFFFu;
        const int np = __popc(field);
        if (np) {                                  // group-uniform branch
          const int row = f * 16 + g * 4 + j;
          unsigned int base = 0;
          if (col == 0) base = atomicAdd(&cnt[row], (unsigned int)np);
          base = __shfl(base, g * 16, 64);         // own group leader: active
          if (pred) {
            const int slot = (int)base + __popc(field & ((1u << col) - 1u));
            if (slot < CAP) {
              lidx[row * RSTR + slot] = wid * 128 + kt * 16 + col;
              lval[row * RSTR + slot] = x;
            }
          }
        }
      }
  __syncthreads();   // barrier 2 (last): lists complete

  // ---- per-wave epilogue: wave wid owns rows {2*wid, 2*wid+1}.
  for (int rr = 0; rr < 2; ++rr) {
    const int row = wid * 2 + rr;
    int n = (int)cnt[row];
    if (PRE) {
      if (n > CAP) {                      // rare Gumbel tail: repair kernel
        if (lane == 0) gflag[(size_t)bh * S_ + qt * QT + row] = 1;
        continue;
      }
    } else {
      if (n > CAP) n = CAP;               // no-ws fallback: clamp
    }

    // registers <- candidate list
    float xv[7]; int iv[7];               // 7*64 = CAP
#pragma unroll
    for (int r = 0; r < 7; ++r) {
      const int i = lane + (r << 6);
      if (i < n) { xv[r] = lval[row * RSTR + i]; iv[r] = lidx[row * RSTR + i]; }
      else       { xv[r] = -1e30f;               iv[r] = 0; }
    }
    // exact Newton from tau0 = m - 1 (restricted f == full f on [tau0, inf);
    // s1 >= 1 below the root since x_max = m is in the list).
    float tw = __shfl(rowmax, row) - 1.0f;
    for (int it = 0; it < WMAXIT; ++it) {
      float s1 = 0.f, s2 = 0.f;
#pragma unroll
      for (int r = 0; r < 7; ++r) {
        float u = fmaxf(xv[r] - tw, 0.f);
        s1 += u; s2 = fmaf(u, u, s2);
      }
#pragma unroll
      for (int off = 1; off < 64; off <<= 1) {
        s1 += __shfl_xor(s1, off, 64);
        s2 += __shfl_xor(s2, off, 64);
      }
      float step = (s2 - 1.0f) / (2.0f * s1);
      tw += step;
      if (step < 1e-7f) break;                  // lane-uniform
    }
    // in-place support compaction via ballot-prefix (no atomics).
    int sn = 0;
#pragma unroll
    for (int r = 0; r < 7; ++r) {
      const float u = xv[r] - tw;
      const bool pred = (u > 0.f) && (lane + (r << 6) < n);
      const unsigned long long mb = __ballot(pred);
      if (pred) {
        const int slot = sn + __popcll(mb & ((1ull << lane) - 1ull));
        lidx[row * RSTR + slot] = iv[r]; lval[row * RSTR + slot] = u * u;
      }
      sn += (int)__popcll(mb);
    }

    // ---- parallel PV: entry subgroup eg = lane>>4 strides over the support,
    // d-column d4 = lane&15 (float4); 2-level butterfly; lanes 0-15 write.
    const int eg = lane >> 4;
    const int d4 = lane & 15;
    float4 a4 = {0.f, 0.f, 0.f, 0.f};
    for (int i = eg; i < sn; i += 4) {
      const float pv = lval[row * RSTR + i];
      const float4 vv = *(const float4*)&vp[(size_t)lidx[row * RSTR + i] * D_ + d4 * 4];
      a4.x = fmaf(pv, vv.x, a4.x); a4.y = fmaf(pv, vv.y, a4.y);
      a4.z = fmaf(pv, vv.z, a4.z); a4.w = fmaf(pv, vv.w, a4.w);
    }
#pragma unroll
    for (int off = 16; off < 64; off <<= 1) {
      a4.x += __shfl_xor(a4.x, off, 64);
      a4.y += __shfl_xor(a4.y, off, 64);
      a4.z += __shfl_xor(a4.z, off, 64);
      a4.w += __shfl_xor(a4.w, off, 64);
    }
    if (lane < 16)
      *(float4*)&op[row * D_ + d4 * 4] = a4;
  }
}

// ============ Repair kernel: exact recompute of flagged rows ============
// Own register budget. Grid-strided waves scan the 32K flags (~3us clean);
// flagged rows get full fp32 QK^T, exact Newton, sparse PV.
__global__ __launch_bounds__(256)
void entmax_repair_kernel(const float* __restrict__ q,
                          const float* __restrict__ k,
                          const float* __restrict__ v,
                          const int* __restrict__ gflag,
                          float* __restrict__ out) {
  __shared__ float qs[4][D_];
  __shared__ int   sidx[4][SUPR];
  __shared__ float sp[4][SUPR];

  const int wid  = threadIdx.x >> 6;
  const int lane = threadIdx.x & 63;
  const int gw   = blockIdx.x * 4 + wid;       // global wave id
  const int nw   = gridDim.x * 4;

  for (int rowg = gw; rowg < NROWS; rowg += nw) {
    if (gflag[rowg] == 0) continue;
    const int bh = rowg >> 11;                 // rowg / S_
    const float* kb = k + (size_t)bh * S_ * D_;
    const float* vb = v + (size_t)bh * S_ * D_;

    qs[wid][lane] = q[(size_t)rowg * D_ + lane] * 0.0625f;  // same-wave: in-order
    float xs[32];
    for (int r = 0; r < 32; ++r) {
      const float* krow = kb + (size_t)(lane + (r << 6)) * D_;
      float d = 0.f;
#pragma unroll 4
      for (int dc = 0; dc < D_; dc += 4) {
        float4 kv4 = *(const float4*)(krow + dc);
        d = fmaf(qs[wid][dc + 0], kv4.x, d);
        d = fmaf(qs[wid][dc + 1], kv4.y, d);
        d = fmaf(qs[wid][dc + 2], kv4.z, d);
        d = fmaf(qs[wid][dc + 3], kv4.w, d);
      }
      xs[r] = d;
    }
    float mx = xs[0];
#pragma unroll
    for (int r = 1; r < 32; ++r) mx = fmaxf(mx, xs[r]);
#pragma unroll
    for (int off = 1; off < 64; off <<= 1) mx = fmaxf(mx, __shfl_xor(mx, off, 64));
    float tau = mx - 1.0f;
    for (int it = 0; it < 32; ++it) {
      float s1 = 0.f, s2 = 0.f;
#pragma unroll
      for (int r = 0; r < 32; ++r) {
        float u = fmaxf(xs[r] - tau, 0.f);
        s1 += u; s2 = fmaf(u, u, s2);
      }
#pragma unroll
      for (int off = 1; off < 64; off <<= 1) {
        s1 += __shfl_xor(s1, off, 64);
        s2 += __shfl_xor(s2, off, 64);
      }
      float step = (s2 - 1.0f) / (2.0f * s1);
      tau += step;
      if (step < 1e-7f) break;
    }
    int sn = 0;
#pragma unroll
    for (int r = 0; r < 32; ++r) {
      const float u = xs[r] - tau;
      const bool pred = u > 0.f;
      const unsigned long long mb = __ballot(pred);
      if (pred) {
        const int slot = sn + __popcll(mb & ((1ull << lane) - 1ull));
        if (slot < SUPR) { sidx[wid][slot] = lane + (r << 6); sp[wid][slot] = u * u; }
      }
      sn += (int)__popcll(mb);
    }
    if (sn > SUPR) sn = SUPR;
    float s = 0.f;
    for (int i = 0; i < sn; ++i)
      s = fmaf(sp[wid][i], vb[(size_t)sidx[wid][i] * D_ + lane], s);
    out[(size_t)rowg * D_ + lane] = s;
  }
}

extern "C" void kernel_launch(void* const* d_in, const int* in_sizes, int n_in,
                              void* d_out, int out_size, void* d_ws, size_t ws_size,
                              hipStream_t stream) {
  const float* q = (const float*)d_in[0];
  const float* k = (const float*)d_in[1];
  const float* v = (const float*)d_in[2];
  float* out = (float*)d_out;
  const size_t khi_b  = (size_t)KELEMS * 2;    // 4 MB each
  const size_t flag_b = (size_t)NROWS * 4;     // 128 KB
  const dim3 grid(BH_ * (S_ / QT));            // 16 * 64 = 1024 blocks

  if (d_ws != nullptr && ws_size >= 2 * khi_b + flag_b) {
    unsigned short* khi = (unsigned short*)d_ws;
    unsigned short* klo = khi + KELEMS;
    int* gflag = (int*)((char*)d_ws + 2 * khi_b);
    ksplit_kernel<<<dim3(KELEMS / (256 * 4)), dim3(256), 0, stream>>>(k, khi, klo, gflag);
    entmax_attn_kernel<true><<<grid, dim3(BLOCK), 0, stream>>>(
        q, k, khi, klo, v, gflag, out);
    entmax_repair_kernel<<<dim3(256), dim3(256), 0, stream>>>(q, k, v, gflag, out);
  } else {
    entmax_attn_kernel<false><<<grid, dim3(BLOCK), 0, stream>>>(
        q, k, nullptr, nullptr, v, nullptr, out);
  }
}